// Round 7
// baseline (2942.270 us; speedup 1.0000x reference)
//
#include <hip/hip_runtime.h>

#define DEV static __device__ __forceinline__

typedef __attribute__((ext_vector_type(8))) short bf16x8;
typedef __attribute__((ext_vector_type(4))) float f32x4;

namespace {
constexpr int SALL  = 22;
constexpr int NAC   = 20;
constexpr int NWIN  = 7;
constexpr int NF    = 16;
constexpr int SPF   = 192;   // 8*24 spatial per frame
constexpr int NTOK  = 768;   // 4*SPF
constexpr int BWIN  = 224;   // NWIN*NB
constexpr int PARTS = 8;
constexpr int TPP   = 3;     // 32-token tiles per part
constexpr float LNEPS = 1e-5f;
constexpr float EPS   = 1e-8f;
constexpr float SCL   = 0.0625f;

// workspace layout (float offsets)
constexpr int OFF_PE   = 0;                         // [768][256]
constexpr int OFF_QWT  = OFF_PE   + 768 * 256;      // q_w transpose
constexpr int OFF_FF1T = OFF_QWT  + 256 * 256;
constexpr int OFF_FF2T = OFF_FF1T + 256 * 256;
constexpr int OFF_GWIT = OFF_FF2T + 256 * 256;      // [256][768]
constexpr int OFF_GWHT = OFF_GWIT + 256 * 768;      // [256][768]
constexpr int OFF_Q    = OFF_GWHT + 256 * 768;      // [22][256]
constexpr int OFF_QK2T = OFF_Q    + SALL * 256;     // [256][22]
constexpr int OFF_QB   = OFF_QK2T + 256 * SALL;     // [32]
constexpr int OFF_HG0  = OFF_QB   + 32;             // [22][768]
constexpr int OFF_WHP  = OFF_HG0  + SALL * 768;     // 3 mats x 128 frags x 64 lanes x uint4
constexpr int OFF_WLP  = OFF_WHP  + 3 * 128 * 64 * 4;
constexpr int OFF_QPH  = OFF_WLP  + 3 * 128 * 64 * 4; // 16 frags x 64 x uint4
constexpr int OFF_QPL  = OFF_QPH  + 16 * 64 * 4;
constexpr int OFF_UPDP = OFF_QPL  + 16 * 64 * 4;    // [1792][20][256]
constexpr int OFF_RSP  = OFF_UPDP + BWIN * PARTS * NAC * 256;
} // namespace

DEV float4 ld4(const float* p) { return *(const float4*)p; }
DEV float sigm(float x) { return 1.f / (1.f + __expf(-x)); }
DEV float bf2(short h) { return __uint_as_float(((unsigned)(unsigned short)h) << 16); }

// one shared swizzle for ALL bf16 LDS buffers: 8-elem (16B) granule XOR'd by row&7
DEV int swzoff(int row, int col) {
    return (row << 8) + (((((col >> 3) ^ (row & 7))) << 3) | (col & 7));
}

DEV void split2(float v, unsigned short& h, unsigned short& l) {
    unsigned u = __float_as_uint(v);
    unsigned hr = (u + 0x7fffu + ((u >> 16) & 1u)) & 0xffff0000u;
    h = (unsigned short)(hr >> 16);
    float lf = v - __uint_as_float(hr);
    unsigned u2 = __float_as_uint(lf);
    l = (unsigned short)((u2 + 0x7fffu + ((u2 >> 16) & 1u)) >> 16);
}

DEV void st_bf16(short* dH, short* dL, int row, int col, float v) {
    unsigned short h, l;
    split2(v, h, l);
    const int off = swzoff(row, col);
    dH[off] = (short)h; dL[off] = (short)l;
}

DEV void st4_bf16(short* dH, short* dL, int row, int c0, float4 o) {
    unsigned short h[4], l[4];
    float vv[4] = {o.x, o.y, o.z, o.w};
#pragma unroll
    for (int i = 0; i < 4; ++i) split2(vv[i], h[i], l[i]);
    const int off = swzoff(row, c0);  // c0 % 4 == 0 -> 8B aligned
    *(uint2*)(dH + off) = make_uint2(h[0] | ((unsigned)h[1] << 16), h[2] | ((unsigned)h[3] << 16));
    *(uint2*)(dL + off) = make_uint2(l[0] | ((unsigned)l[1] << 16), l[2] | ((unsigned)l[3] << 16));
}

DEV f32x4 mm(bf16x8 a, bf16x8 b, f32x4 c) {
    return __builtin_amdgcn_mfma_f32_16x16x32_bf16(a, b, c, 0, 0, 0);
}
DEV f32x4 mm3(bf16x8 ah, bf16x8 al, bf16x8 bh, bf16x8 bl, f32x4 c) {
    c = mm(al, bh, c);
    c = mm(ah, bl, c);
    c = mm(ah, bh, c);
    return c;
}

// ---------------------------------------------------------------- transposes
struct TPtrs {
    const float* src[8];
    float*       dst[8];
    int          osz[8];
};

__global__ void k_trans(TPtrs p) {
    __shared__ float t[32][33];
    const int bt = blockIdx.x;
    int m, tile;
    if (bt < 192) { m = bt >> 6; tile = bt & 63; }
    else          { m = 3 + (bt - 192) / 192; tile = (bt - 192) % 192; }
    const int O  = p.osz[m];
    const int rt = O >> 5;
    const int o0 = (tile % rt) * 32, i0 = (tile / rt) * 32;
    const int tx = threadIdx.x & 31, ty = threadIdx.x >> 5;
    const float* src = p.src[m];
    float*       dst = p.dst[m];
#pragma unroll
    for (int q = 0; q < 4; ++q) { int r = ty + q * 8; t[r][tx] = src[(o0 + r) * 256 + i0 + tx]; }
    __syncthreads();
#pragma unroll
    for (int q = 0; q < 4; ++q) { int r = ty + q * 8; dst[(i0 + r) * O + o0 + tx] = t[tx][r]; }
}

// ---------------------------------------------------------------- pe table
__global__ void k_pe(const float* __restrict__ pw, const float* __restrict__ pb,
                     float* __restrict__ pe) {
    const int p = blockIdx.x;
    const int fo = p / SPF, rem = p % SPF, hh = rem / 24, ww = rem % 24;
    const float g0 = fo * (1.f / 3.f), g1 = hh * (1.f / 7.f), g2 = ww * (1.f / 23.f);
    const float gg[6] = {g0, g1, g2, 1.f - g0, 1.f - g1, 1.f - g2};
    for (int d = threadIdx.x; d < 256; d += 64) {
        float acc = pb[d];
#pragma unroll
        for (int c = 0; c < 6; ++c) acc = fmaf(gg[c], pw[d * 6 + c], acc);
        pe[p * 256 + d] = acc;
    }
}

// ---------------------------------------------------------------- q + qb
__global__ void k_q(const float* __restrict__ slots, const float* __restrict__ nsg,
                    const float* __restrict__ nsb, const float* __restrict__ qwT,
                    const float* __restrict__ qbias, const float* __restrict__ kb,
                    float* __restrict__ qout, float* __restrict__ qbout) {
    __shared__ float lnb[256];
    __shared__ float red[8];
    const int i = blockIdx.x, t = threadIdx.x, lane = t & 63, wvi = t >> 6;
    const float v = slots[i * 256 + t];
    float s1 = v, s2 = v * v;
#pragma unroll
    for (int m = 32; m; m >>= 1) { s1 += __shfl_xor(s1, m); s2 += __shfl_xor(s2, m); }
    if (lane == 0) { red[wvi] = s1; red[4 + wvi] = s2; }
    __syncthreads();
    const float fs = red[0] + red[1] + red[2] + red[3];
    const float fq = red[4] + red[5] + red[6] + red[7];
    const float mean = fs * (1.f / 256.f);
    const float var  = fq * (1.f / 256.f) - mean * mean;
    const float rstd = rsqrtf(var + LNEPS);
    lnb[t] = (v - mean) * rstd * nsg[t] + nsb[t];
    __syncthreads();
    float qv = qbias[t];
    for (int k = 0; k < 256; ++k) qv = fmaf(lnb[k], qwT[k * 256 + t], qv);
    qout[i * 256 + t] = qv;
    float pp = qv * kb[t];
#pragma unroll
    for (int m = 32; m; m >>= 1) pp += __shfl_xor(pp, m);
    __syncthreads();
    if (lane == 0) red[wvi] = pp;
    __syncthreads();
    if (t == 0) qbout[i] = red[0] + red[1] + red[2] + red[3];
}

// ---------------------------------------------------------------- qk2T[k][i]
__global__ void k_qk2(const float* __restrict__ qin, const float* __restrict__ kw,
                      float* __restrict__ qk2T) {
    __shared__ float qr[256];
    const int i = blockIdx.x, t = threadIdx.x;
    qr[t] = qin[i * 256 + t];
    __syncthreads();
    float acc = 0.f;
    for (int c = 0; c < 256; ++c) acc = fmaf(qr[c], kw[c * 256 + t], acc);
    qk2T[t * SALL + i] = acc;
}

// ---------------------------------------------------------------- hg0
__global__ void k_hg(const float* __restrict__ slots, const float* __restrict__ gwhT,
                     const float* __restrict__ gbh, float* __restrict__ hg0) {
    __shared__ float sr[256];
    const int i = blockIdx.x, t = threadIdx.x;
    sr[t] = slots[i * 256 + t];
    __syncthreads();
    float a0 = gbh[t], a1 = gbh[t + 256], a2 = gbh[t + 512];
    for (int k = 0; k < 256; ++k) {
        const float s = sr[k];
        a0 = fmaf(s, gwhT[k * 768 + t], a0);
        a1 = fmaf(s, gwhT[k * 768 + t + 256], a1);
        a2 = fmaf(s, gwhT[k * 768 + t + 512], a2);
    }
    hg0[i * 768 + t] = a0;
    hg0[i * 768 + t + 256] = a1;
    hg0[i * 768 + t + 512] = a2;
}

// ---------------------------------------------------------------- W fragment packer
// frag (Nfg,Kf): lane l holds 8 bf16 of B[k][n]=W[n][k], n=Nfg*16+(l&15), k=Kf*32+(l>>4)*8+j
__global__ void k_wpack(const float* __restrict__ w0, const float* __restrict__ w1,
                        const float* __restrict__ w2, uint4* __restrict__ hp,
                        uint4* __restrict__ lp) {
    const int b = blockIdx.x;            // 384
    const int m = b >> 7, f = b & 127;
    const int Nfg = f >> 3, Kf = f & 7;
    const int l = threadIdx.x;           // 64
    const float* W = (m == 0) ? w0 : ((m == 1) ? w1 : w2);
    const int col = (Nfg << 4) + (l & 15);
    const int k0  = (Kf << 5) + ((l >> 4) << 3);
    unsigned short h[8], lo[8];
#pragma unroll
    for (int j = 0; j < 8; ++j) split2(W[col * 256 + k0 + j], h[j], lo[j]);
    const int idx = ((m << 7) + f) * 64 + l;
    hp[idx] = make_uint4(h[0] | ((unsigned)h[1] << 16), h[2] | ((unsigned)h[3] << 16),
                         h[4] | ((unsigned)h[5] << 16), h[6] | ((unsigned)h[7] << 16));
    lp[idx] = make_uint4(lo[0] | ((unsigned)lo[1] << 16), lo[2] | ((unsigned)lo[3] << 16),
                         lo[4] | ((unsigned)lo[5] << 16), lo[6] | ((unsigned)lo[7] << 16));
}

// ---------------------------------------------------------------- qk2 fragment packer (A of dots, M=32 pad)
__global__ void k_qpk(const float* __restrict__ qk2T, uint4* __restrict__ hp,
                      uint4* __restrict__ lp) {
    const int b = blockIdx.x;            // 16: Mf = b>>3, Kf = b&7
    const int l = threadIdx.x;
    const int slot = ((b >> 3) << 4) + (l & 15);
    const int k0   = ((b & 7) << 5) + ((l >> 4) << 3);
    unsigned short h[8], lo[8];
#pragma unroll
    for (int j = 0; j < 8; ++j) {
        float v = (slot < SALL) ? qk2T[(k0 + j) * SALL + slot] : 0.f;
        split2(v, h[j], lo[j]);
    }
    const int idx = b * 64 + l;
    hp[idx] = make_uint4(h[0] | ((unsigned)h[1] << 16), h[2] | ((unsigned)h[3] << 16),
                         h[4] | ((unsigned)h[5] << 16), h[6] | ((unsigned)h[7] << 16));
    lp[idx] = make_uint4(lo[0] | ((unsigned)lo[1] << 16), lo[2] | ((unsigned)lo[3] << 16),
                         lo[4] | ((unsigned)lo[5] << 16), lo[6] | ((unsigned)lo[7] << 16));
}

// ---------------------------------------------------------------- MFMA gemm step
// 32 tokens x 256 out-cols, K=256. Wave wv -> cols [wv*64, wv*64+64): 2 Mf x 4 Nf x 8 Kf.
// A layout: row = lane&15 (+16*Mf), k = Kf*32 + (lane>>4)*8 + j (8 consecutive).
// C layout (m89): col = lane&15, row = (lane>>4)*4 + reg.
// MODE 0: relu; MODE 1: LayerNorm(ni) across full 256-col rows (cross-wave); MODE 2: plain.
template <int MODE>
DEV void mfma_step(const short* sH, const short* sL, short* dH, short* dL,
                   const bf16x8* __restrict__ wph, const bf16x8* __restrict__ wpl,
                   const float* bs, const float* gs, const float* bns,
                   const int lane, const int wv, const int tid,
                   float* lnpart, float* lnstat) {
    f32x4 acc[2][4];
#pragma unroll
    for (int Mf = 0; Mf < 2; ++Mf)
#pragma unroll
        for (int Nf = 0; Nf < 4; ++Nf) {
            const float b = bs[Nf];
            acc[Mf][Nf] = (f32x4){b, b, b, b};
        }
    const int ar0 = lane & 15, ar1 = 16 + (lane & 15);
    const int gkb = lane >> 4;
#pragma unroll
    for (int Kf = 0; Kf < 8; ++Kf) {
        const int c8 = (Kf * 4 + gkb) << 3;
        const bf16x8 a0h = *(const bf16x8*)(sH + swzoff(ar0, c8));
        const bf16x8 a0l = *(const bf16x8*)(sL + swzoff(ar0, c8));
        const bf16x8 a1h = *(const bf16x8*)(sH + swzoff(ar1, c8));
        const bf16x8 a1l = *(const bf16x8*)(sL + swzoff(ar1, c8));
#pragma unroll
        for (int Nf = 0; Nf < 4; ++Nf) {
            const int fidx = (((wv << 2) + Nf) * 8 + Kf) * 64 + lane;
            const bf16x8 bh = wph[fidx];
            const bf16x8 bl = wpl[fidx];
            acc[0][Nf] = mm3(a0h, a0l, bh, bl, acc[0][Nf]);
            acc[1][Nf] = mm3(a1h, a1l, bh, bl, acc[1][Nf]);
        }
    }
    const int rb = (lane >> 4) << 2;
    const int cb = (wv << 6) + (lane & 15);
    if constexpr (MODE == 1) {
        // cross-wave LayerNorm: per-row sums (cols split across 16-lane groups and 4 waves)
#pragma unroll
        for (int Mf = 0; Mf < 2; ++Mf)
#pragma unroll
            for (int r = 0; r < 4; ++r) {
                float s  = acc[Mf][0][r] + acc[Mf][1][r] + acc[Mf][2][r] + acc[Mf][3][r];
                float s2 = acc[Mf][0][r] * acc[Mf][0][r] + acc[Mf][1][r] * acc[Mf][1][r] +
                           acc[Mf][2][r] * acc[Mf][2][r] + acc[Mf][3][r] * acc[Mf][3][r];
#pragma unroll
                for (int m = 1; m < 16; m <<= 1) { s += __shfl_xor(s, m); s2 += __shfl_xor(s2, m); }
                if ((lane & 15) == 0) {
                    const int row = (Mf << 4) + rb + r;
                    lnpart[(wv * 32 + row) * 2]     = s;
                    lnpart[(wv * 32 + row) * 2 + 1] = s2;
                }
            }
        __syncthreads();
        if (tid < 32) {
            float s = 0.f, s2 = 0.f;
#pragma unroll
            for (int w = 0; w < 4; ++w) {
                s  += lnpart[(w * 32 + tid) * 2];
                s2 += lnpart[(w * 32 + tid) * 2 + 1];
            }
            const float mean = s * (1.f / 256.f);
            const float var  = s2 * (1.f / 256.f) - mean * mean;
            lnstat[tid * 2]     = mean;
            lnstat[tid * 2 + 1] = rsqrtf(var + LNEPS);
        }
        __syncthreads();
    }
#pragma unroll
    for (int Mf = 0; Mf < 2; ++Mf)
#pragma unroll
        for (int Nf = 0; Nf < 4; ++Nf)
#pragma unroll
            for (int r = 0; r < 4; ++r) {
                float v = acc[Mf][Nf][r];
                const int row = (Mf << 4) + rb + r;
                const int col = cb + (Nf << 4);
                if constexpr (MODE == 0) v = fmaxf(v, 0.f);
                if constexpr (MODE == 1)
                    v = (v - lnstat[row * 2]) * lnstat[row * 2 + 1] * gs[Nf] + bns[Nf];
                st_bf16(dH, dL, row, col, v);
            }
}

// ---------------------------------------------------------------- pass 1
__global__ __launch_bounds__(256, 2) void k_pass1(
    const float* __restrict__ gin, const float* __restrict__ ws_pe,
    const bf16x8* __restrict__ whp, const bf16x8* __restrict__ wlp,
    const bf16x8* __restrict__ qph, const bf16x8* __restrict__ qpl,
    const float* __restrict__ qb, const float* __restrict__ LNg,
    const float* __restrict__ LNb, const float* __restrict__ nig,
    const float* __restrict__ nib, const float* __restrict__ fc1b,
    const float* __restrict__ fc2b, const float* __restrict__ vb,
    float* __restrict__ attns, float* __restrict__ updp, float* __restrict__ rsp) {
    __shared__ __align__(16) short xAh[32 * 256];
    __shared__ __align__(16) short xAl[32 * 256];
    __shared__ __align__(16) short xBh[32 * 256];
    __shared__ __align__(16) short xBl[32 * 256];
    __shared__ __align__(16) float dotsL[SALL * 36];
    __shared__ float lnpart[4 * 32 * 2];
    __shared__ float lnstat[32 * 2];

    const int tid = threadIdx.x, lane = tid & 63, wv = tid >> 6;
    const int blk = blockIdx.x, bb = blk >> 3, part = blk & 7;
    const int wdx = bb >> 5, bi = bb & 31;

    // step-1 (LN over input+PE) per-lane float4 column base
    const int c0 = lane << 2;
    const float4 gln = ld4(LNg + c0), bln = ld4(LNb + c0);

    // MFMA epilogue per-thread column scalars: col = cb + Nf*16
    const int cb = (wv << 6) + (lane & 15);
    float b1s[4], b2s[4], bvs[4], gnis[4], bnis[4];
#pragma unroll
    for (int Nf = 0; Nf < 4; ++Nf) {
        b1s[Nf]  = fc1b[cb + (Nf << 4)];
        b2s[Nf]  = fc2b[cb + (Nf << 4)];
        bvs[Nf]  = vb[cb + (Nf << 4)];
        gnis[Nf] = nig[cb + (Nf << 4)];
        bnis[Nf] = nib[cb + (Nf << 4)];
    }
    // qb per potential slot-row of dots C-tile
    float qb8[8];
#pragma unroll
    for (int Mf = 0; Mf < 2; ++Mf)
#pragma unroll
        for (int r = 0; r < 4; ++r) {
            const int s_ = (Mf << 4) + ((lane >> 4) << 2) + r;
            qb8[(Mf << 2) + r] = qb[s_ < SALL ? s_ : SALL - 1];
        }

    const bf16x8* wph1 = whp;           const bf16x8* wpl1 = wlp;
    const bf16x8* wph2 = whp + 8192;    const bf16x8* wpl2 = wlp + 8192;
    const bf16x8* wphv = whp + 16384;   const bf16x8* wplv = wlp + 16384;

    float upd[NAC];
#pragma unroll
    for (int i = 0; i < NAC; ++i) upd[i] = 0.f;
    float rsacc = 0.f;

    for (int tt = part * TPP; tt < part * TPP + TPP; ++tt) {
        const int fo = tt / 6, sp0 = (tt % 6) * 32;
        const float4* src = (const float4*)gin + ((bi * NF + 2 * wdx + fo) * SPF + sp0) * 64;
        const float4* pes = (const float4*)ws_pe + (fo * SPF + sp0) * 64;
        // ---- step 1: load + PE + LN(LN) -> pair A (bf16 hi/lo, swizzled) ----
#pragma unroll
        for (int ii = 0; ii < 8; ++ii) {
            float4 a = src[tid + 256 * ii];
            const float4 p = pes[tid + 256 * ii];
            a.x += p.x; a.y += p.y; a.z += p.z; a.w += p.w;
            float s  = a.x + a.y + a.z + a.w;
            float q2 = a.x * a.x + a.y * a.y + a.z * a.z + a.w * a.w;
#pragma unroll
            for (int m = 32; m; m >>= 1) { s += __shfl_xor(s, m); q2 += __shfl_xor(q2, m); }
            const float mean = s * (1.f / 256.f);
            const float var  = q2 * (1.f / 256.f) - mean * mean;
            const float rstd = rsqrtf(var + LNEPS);
            const int j = wv + (ii << 2);  // wave-owned token
            float4 o;
            o.x = (a.x - mean) * rstd * gln.x + bln.x;
            o.y = (a.y - mean) * rstd * gln.y + bln.y;
            o.z = (a.z - mean) * rstd * gln.z + bln.z;
            o.w = (a.w - mean) * rstd * gln.w + bln.w;
            st4_bf16(xAh, xAl, j, c0, o);
        }
        __syncthreads();
        // ---- step 2: FC1 + relu : A -> B ----
        mfma_step<0>(xAh, xAl, xBh, xBl, wph1, wpl1, b1s, gnis, bnis, lane, wv, tid, lnpart, lnstat);
        __syncthreads();
        // ---- step 3: FC2 + LN(ni) : B -> A (xn) ----
        mfma_step<1>(xBh, xBl, xAh, xAl, wph2, wpl2, b2s, gnis, bnis, lane, wv, tid, lnpart, lnstat);
        __syncthreads();
        // ---- step 4: V : A -> B (vv) ; wave0 additionally computes dots via MFMA ----
        mfma_step<2>(xAh, xAl, xBh, xBl, wphv, wplv, bvs, gnis, bnis, lane, wv, tid, lnpart, lnstat);
        if (wv == 0) {
            // dots(32pad x 32) = qk2(32x256) . xn^T ; B[k][tok]=xn[tok][k] -> same LDS frag reads
            f32x4 dacc[2][2];
#pragma unroll
            for (int Mf = 0; Mf < 2; ++Mf)
#pragma unroll
                for (int Nf = 0; Nf < 2; ++Nf) dacc[Mf][Nf] = (f32x4){0.f, 0.f, 0.f, 0.f};
            const int tr0 = lane & 15, tr1 = 16 + (lane & 15);
#pragma unroll
            for (int Kf = 0; Kf < 8; ++Kf) {
                const int c8 = (Kf * 4 + (lane >> 4)) << 3;
                const bf16x8 b0h = *(const bf16x8*)(xAh + swzoff(tr0, c8));
                const bf16x8 b0l = *(const bf16x8*)(xAl + swzoff(tr0, c8));
                const bf16x8 b1h = *(const bf16x8*)(xAh + swzoff(tr1, c8));
                const bf16x8 b1l = *(const bf16x8*)(xAl + swzoff(tr1, c8));
#pragma unroll
                for (int Mf = 0; Mf < 2; ++Mf) {
                    const bf16x8 ah = qph[(Mf * 8 + Kf) * 64 + lane];
                    const bf16x8 al = qpl[(Mf * 8 + Kf) * 64 + lane];
                    dacc[Mf][0] = mm3(ah, al, b0h, b0l, dacc[Mf][0]);
                    dacc[Mf][1] = mm3(ah, al, b1h, b1l, dacc[Mf][1]);
                }
            }
#pragma unroll
            for (int Mf = 0; Mf < 2; ++Mf)
#pragma unroll
                for (int Nf = 0; Nf < 2; ++Nf)
#pragma unroll
                    for (int r = 0; r < 4; ++r) {
                        const int slot = (Mf << 4) + ((lane >> 4) << 2) + r;
                        const int tok  = (Nf << 4) + (lane & 15);
                        if (slot < SALL)
                            dotsL[slot * 36 + tok] = (dacc[Mf][Nf][r] + qb8[(Mf << 2) + r]) * SCL;
                    }
        }
        __syncthreads();
        // ---- step 5: softmax over 22 slots per token ----
        if (tid < 32) {
            float dv[SALL];
            float mx = -1e30f;
#pragma unroll
            for (int i = 0; i < SALL; ++i) { dv[i] = dotsL[i * 36 + tid]; mx = fmaxf(mx, dv[i]); }
            float sum = 0.f;
#pragma unroll
            for (int i = 0; i < SALL; ++i) { dv[i] = __expf(dv[i] - mx); sum += dv[i]; }
            const float inv = 1.f / sum;
#pragma unroll
            for (int i = 0; i < SALL; ++i) dotsL[i * 36 + tid] = dv[i] * inv + EPS;
        }
        __syncthreads();
        // ---- step 6: attns out + rowsum + upd ----
        const int tok0 = tt * 32;
        float* ao = attns + bi * (NWIN * SALL * NTOK) + wdx * (SALL * NTOK) + tok0;
#pragma unroll
        for (int rep = 0; rep < 3; ++rep) {
            const int idx = tid + rep * 256;
            if (idx < SALL * 32) {
                const int i = idx >> 5, j = idx & 31;
                ao[i * NTOK + j] = dotsL[i * 36 + j];
            }
        }
        if (tid < NAC) {
            float s = 0.f;
#pragma unroll
            for (int j = 0; j < 32; ++j) s += dotsL[tid * 36 + j];
            rsacc += s;
        }
        // upd[i][d=tid] += sum_j a[i][j]*vv[j][d]; vv = hi+lo reconstruct from pair B
#pragma unroll
        for (int jq = 0; jq < 8; ++jq) {
            const float v0 = bf2(xBh[swzoff(jq * 4 + 0, tid)]) + bf2(xBl[swzoff(jq * 4 + 0, tid)]);
            const float v1 = bf2(xBh[swzoff(jq * 4 + 1, tid)]) + bf2(xBl[swzoff(jq * 4 + 1, tid)]);
            const float v2 = bf2(xBh[swzoff(jq * 4 + 2, tid)]) + bf2(xBl[swzoff(jq * 4 + 2, tid)]);
            const float v3 = bf2(xBh[swzoff(jq * 4 + 3, tid)]) + bf2(xBl[swzoff(jq * 4 + 3, tid)]);
#pragma unroll
            for (int i = 0; i < NAC; ++i) {
                const float4 a = *(const float4*)&dotsL[i * 36 + jq * 4];
                upd[i] = fmaf(a.x, v0, fmaf(a.y, v1, fmaf(a.z, v2, fmaf(a.w, v3, upd[i]))));
            }
        }
        __syncthreads();  // buffers reused next tile
    }
    float* up = updp + blk * (NAC * 256);
#pragma unroll
    for (int i = 0; i < NAC; ++i) up[i * 256 + tid] = upd[i];
    if (tid < NAC) rsp[blk * NAC + tid] = rsacc;
}

// ---------------------------------------------------------------- pass 2: GRU + residual MLP
__global__ __launch_bounds__(256) void k_pass2(
    const float* __restrict__ updp, const float* __restrict__ rsp,
    const float* __restrict__ gwiT, const float* __restrict__ gbi,
    const float* __restrict__ hg0, const float* __restrict__ slots,
    const float* __restrict__ npfg, const float* __restrict__ npfb,
    const float* __restrict__ ff1T, const float* __restrict__ ff1b,
    const float* __restrict__ ff2T, const float* __restrict__ ff2b,
    float* __restrict__ sout) {
    __shared__ float u[256];
    __shared__ float red[8];
    const int t = threadIdx.x, lane = t & 63, wvi = t >> 6;
    const int blk = blockIdx.x, bb = blk >> 2, sg = blk & 3;
    const int wdx = bb >> 5, bi = bb & 31;
    const float* upb = updp + (bb * PARTS) * (NAC * 256);
    const float* rsb = rsp + (bb * PARTS) * NAC;
    for (int m = 0; m < 5; ++m) {
        const int i = sg * 5 + m;
        float rs = 0.f, uv = 0.f;
#pragma unroll
        for (int p = 0; p < PARTS; ++p) {
            rs += rsb[p * NAC + i];
            uv += upb[p * (NAC * 256) + i * 256 + t];
        }
        uv /= rs;
        u[t] = uv;
        __syncthreads();
        float a0 = gbi[t], a1 = gbi[t + 256], a2 = gbi[t + 512];
        for (int k = 0; k < 256; ++k) {
            const float s = u[k];
            a0 = fmaf(s, gwiT[k * 768 + t], a0);
            a1 = fmaf(s, gwiT[k * 768 + t + 256], a1);
            a2 = fmaf(s, gwiT[k * 768 + t + 512], a2);
        }
        const float r = sigm(a0 + hg0[i * 768 + t]);
        const float z = sigm(a1 + hg0[i * 768 + t + 256]);
        const float n = tanhf(a2 + r * hg0[i * 768 + t + 512]);
        const float hp = slots[i * 256 + t];
        const float h = (1.f - z) * n + z * hp;
        float s1 = h, s2 = h * h;
#pragma unroll
        for (int mm = 32; mm; mm >>= 1) { s1 += __shfl_xor(s1, mm); s2 += __shfl_xor(s2, mm); }
        __syncthreads();
        if (lane == 0) { red[wvi] = s1; red[4 + wvi] = s2; }
        __syncthreads();
        const float fs = red[0] + red[1] + red[2] + red[3];
        const float fq = red[4] + red[5] + red[6] + red[7];
        const float mean = fs * (1.f / 256.f);
        const float var  = fq * (1.f / 256.f) - mean * mean;
        const float rstd = rsqrtf(var + LNEPS);
        u[t] = (h - mean) * rstd * npfg[t] + npfb[t];
        __syncthreads();
        float f1 = ff1b[t];
        for (int k = 0; k < 256; ++k) f1 = fmaf(u[k], ff1T[k * 256 + t], f1);
        f1 = fmaxf(f1, 0.f);
        __syncthreads();
        u[t] = f1;
        __syncthreads();
        float f2 = ff2b[t];
        for (int k = 0; k < 256; ++k) f2 = fmaf(u[k], ff2T[k * 256 + t], f2);
        sout[bi * (NWIN * NAC * 256) + wdx * (NAC * 256) + i * 256 + t] = h + f2;
        __syncthreads();
    }
}

// ---------------------------------------------------------------- launcher
extern "C" void kernel_launch(void* const* d_in, const int* in_sizes, int n_in,
                              void* d_out, int out_size, void* d_ws, size_t ws_size,
                              hipStream_t stream) {
    const float* inputs = (const float*)d_in[0];
    const float* slots  = (const float*)d_in[1];
    const float* pe_w   = (const float*)d_in[2];
    const float* pe_b   = (const float*)d_in[3];
    const float* LN_g   = (const float*)d_in[4];
    const float* LN_b   = (const float*)d_in[5];
    const float* ni_g   = (const float*)d_in[6];
    const float* ni_b   = (const float*)d_in[7];
    const float* ns_g   = (const float*)d_in[8];
    const float* ns_b   = (const float*)d_in[9];
    const float* npf_g  = (const float*)d_in[10];
    const float* npf_b  = (const float*)d_in[11];
    const float* FC1_w  = (const float*)d_in[12];
    const float* FC1_b  = (const float*)d_in[13];
    const float* FC2_w  = (const float*)d_in[14];
    const float* FC2_b  = (const float*)d_in[15];
    const float* q_w    = (const float*)d_in[16];
    const float* q_b    = (const float*)d_in[17];
    const float* k_w    = (const float*)d_in[18];
    const float* k_b    = (const float*)d_in[19];
    const float* v_w    = (const float*)d_in[20];
    const float* v_b    = (const float*)d_in[21];
    const float* ff1_w  = (const float*)d_in[22];
    const float* ff1_b  = (const float*)d_in[23];
    const float* ff2_w  = (const float*)d_in[24];
    const float* ff2_b  = (const float*)d_in[25];
    const float* gru_wi = (const float*)d_in[26];
    const float* gru_wh = (const float*)d_in[27];
    const float* gru_bi = (const float*)d_in[28];
    const float* gru_bh = (const float*)d_in[29];

    float* ws    = (float*)d_ws;
    float* out   = (float*)d_out;
    float* attns = out + 32 * 7 * 20 * 256;

    TPtrs tp;
    tp.src[0] = q_w;    tp.dst[0] = ws + OFF_QWT;  tp.osz[0] = 256;
    tp.src[1] = ff1_w;  tp.dst[1] = ws + OFF_FF1T; tp.osz[1] = 256;
    tp.src[2] = ff2_w;  tp.dst[2] = ws + OFF_FF2T; tp.osz[2] = 256;
    tp.src[3] = gru_wi; tp.dst[3] = ws + OFF_GWIT; tp.osz[3] = 768;
    tp.src[4] = gru_wh; tp.dst[4] = ws + OFF_GWHT; tp.osz[4] = 768;
    tp.src[5] = q_w;    tp.dst[5] = ws + OFF_QWT;  tp.osz[5] = 256;  // unused
    tp.src[6] = q_w;    tp.dst[6] = ws + OFF_QWT;  tp.osz[6] = 256;  // unused
    tp.src[7] = q_w;    tp.dst[7] = ws + OFF_QWT;  tp.osz[7] = 256;  // unused

    k_trans<<<576, 256, 0, stream>>>(tp);
    k_pe<<<768, 64, 0, stream>>>(pe_w, pe_b, ws + OFF_PE);
    k_q<<<SALL, 256, 0, stream>>>(slots, ns_g, ns_b, ws + OFF_QWT, q_b, k_b,
                                  ws + OFF_Q, ws + OFF_QB);
    k_qk2<<<SALL, 256, 0, stream>>>(ws + OFF_Q, k_w, ws + OFF_QK2T);
    k_hg<<<SALL, 256, 0, stream>>>(slots, ws + OFF_GWHT, gru_bh, ws + OFF_HG0);
    k_wpack<<<384, 64, 0, stream>>>(FC1_w, FC2_w, v_w,
                                    (uint4*)(ws + OFF_WHP), (uint4*)(ws + OFF_WLP));
    k_qpk<<<16, 64, 0, stream>>>(ws + OFF_QK2T,
                                 (uint4*)(ws + OFF_QPH), (uint4*)(ws + OFF_QPL));
    k_pass1<<<BWIN * PARTS, 256, 0, stream>>>(
        inputs, ws + OFF_PE,
        (const bf16x8*)(ws + OFF_WHP), (const bf16x8*)(ws + OFF_WLP),
        (const bf16x8*)(ws + OFF_QPH), (const bf16x8*)(ws + OFF_QPL),
        ws + OFF_QB, LN_g, LN_b, ni_g, ni_b, FC1_b, FC2_b, v_b,
        attns, ws + OFF_UPDP, ws + OFF_RSP);
    k_pass2<<<BWIN * 4, 256, 0, stream>>>(
        ws + OFF_UPDP, ws + OFF_RSP, ws + OFF_GWIT, gru_bi, ws + OFF_HG0, slots,
        npf_g, npf_b, ws + OFF_FF1T, ff1_b, ws + OFF_FF2T, ff2_b, out);
}